// Round 10
// baseline (310.016 us; speedup 1.0000x reference)
//
#include <hip/hip_runtime.h>
#include <hip/hip_bf16.h>

#define N_NODES 100000
#define N_EDGES 800000
#define D 64
#define SCAN_B 256
#define NB1 ((N_NODES + SCAN_B - 1) / SCAN_B)   // 391 blocks
#define FILL_BLOCKS (N_EDGES / 256)             // 3125, exact
#define INIT_BLOCKS (N_NODES * D / 256)         // 25000, exact
#define CT 64                                   // conv tile: nodes per block
#define XS 68                                   // fp32 LDS row stride (bank-safe)
#define OS 72                                   // u16 LDS out row stride

// bf16 helpers: storage-only bf16 (embeds); all math in fp32.
__device__ __forceinline__ unsigned short f2bf(float f) {
    union { float f; unsigned u; } v; v.f = f;
    unsigned r = v.u + 0x7fffu + ((v.u >> 16) & 1u);   // round-to-nearest-even
    return (unsigned short)(r >> 16);
}
__device__ __forceinline__ float bf2f(unsigned short u) {
    return __uint_as_float(((unsigned)u) << 16);
}

// ---------------------------------------------------------------------------
// hist + rank: deg[dst]++, rank[e] = arrival order of edge e at its dst.
__global__ __launch_bounds__(256) void hist_rank_kernel(
        const int2* __restrict__ edges,
        int* __restrict__ deg,
        int* __restrict__ rank) {
    int t = blockIdx.x * 256 + threadIdx.x;
    int2 e = edges[t];                      // grid exact: 3125*256 == N_EDGES
    rank[t] = atomicAdd(&deg[e.y], 1);
}

// ---------------------------------------------------------------------------
// scan1: block-local exclusive scan over deg -> row_ptr, emit block totals.
__global__ void scan1_kernel(const int* __restrict__ deg,
                             int* __restrict__ row_ptr,
                             int* __restrict__ bsum) {
    __shared__ int tmp[SCAN_B];
    int t = threadIdx.x;
    int i = blockIdx.x * SCAN_B + t;
    int v = (i < N_NODES) ? deg[i] : 0;
    tmp[t] = v;
    __syncthreads();
#pragma unroll
    for (int off = 1; off < SCAN_B; off <<= 1) {
        int a = (t >= off) ? tmp[t - off] : 0;
        __syncthreads();
        tmp[t] += a;
        __syncthreads();
    }
    if (i < N_NODES) row_ptr[i] = tmp[t] - v;   // exclusive
    if (t == SCAN_B - 1) bsum[blockIdx.x] = tmp[t];
}

// scan2+scan3 merged: each block reduce-sums bsum[0..blockIdx-1] (391 ints,
// trivially cheap) and adds it to its 256 row_ptr entries. One dispatch fewer.
__global__ void scan23_kernel(int* __restrict__ row_ptr,
                              const int* __restrict__ bsum) {
    __shared__ int red[SCAN_B];
    int t = threadIdx.x;
    int partial = 0;
    if (t < blockIdx.x && t < NB1) partial += bsum[t];
    int t2 = t + 256;
    if (t2 < blockIdx.x && t2 < NB1) partial += bsum[t2];
    red[t] = partial;
    __syncthreads();
#pragma unroll
    for (int off = 128; off > 0; off >>= 1) {
        if (t < off) red[t] += red[t + off];
        __syncthreads();
    }
    int boff = red[0];
    int i = blockIdx.x * SCAN_B + t;
    if (i < N_NODES) row_ptr[i] += boff;
    if (i == 0) row_ptr[N_NODES] = N_EDGES;
}

// ---------------------------------------------------------------------------
// Fused dispatch: blocks [0, FILL_BLOCKS) scatter CSR cols (atomic-free via
// rank); blocks [FILL_BLOCKS, +INIT_BLOCKS) compute initial embeddings (bf16).
__global__ __launch_bounds__(256) void fill_init_kernel(
        const int2* __restrict__ edges,
        const int* __restrict__ rank,
        const int* __restrict__ rowp,
        int* __restrict__ col,
        const int* __restrict__ nodes,
        const float* __restrict__ features,
        const float* __restrict__ node_emb,
        const float* __restrict__ feat_W,
        const float* __restrict__ feat_b,
        unsigned short* __restrict__ embeds) {
    if (blockIdx.x < FILL_BLOCKS) {
        int t = blockIdx.x * 256 + threadIdx.x;
        int2 e = edges[t];
        col[rowp[e.y] + rank[t]] = e.x;
    } else {
        int tid = (blockIdx.x - FILL_BLOCKS) * 256 + threadIdx.x;
        int node = tid >> 6;
        int d = tid & 63;
        float acc = feat_b[d];
        const float* f = features + (size_t)node * 10;
        const float* w = feat_W + (size_t)d * 10;
#pragma unroll
        for (int j = 0; j < 10; ++j) acc += f[j] * w[j];
        embeds[tid] = f2bf(node_emb[(size_t)nodes[node] * D + d] + acc);
    }
}

// ---------------------------------------------------------------------------
// x[node] = emb_in[node] + sum_{src} emb_in[src]   (emb bf16, acc fp32)
// SHUFFLE-FREE: one wave per node, lane = dim. Each src row is one coalesced
// 128-B load (64 lanes x u16); accumulation is per-lane, NO cross-lane reduce
// (the old 8-group design paid ~25 ds_bpermute/node -> LDS-pipe-bound).
// Neighbor idx: one 8-lane col load, broadcast via __shfl(idx, literal r)
// == v_readlane (SALU, no LDS). `r < nb` is wave-uniform -> scalar branch.
// ~20 VGPRs -> full 8 waves/SIMD occupancy.
__global__ __launch_bounds__(256) void gather_x_kernel(
        const unsigned short* __restrict__ emb_in,
        const int* __restrict__ rowp,
        const int* __restrict__ col,
        float* __restrict__ x_out) {
    int lane = threadIdx.x & 63;
    int wv   = threadIdx.x >> 6;
    int node = blockIdx.x * 4 + wv;          // grid = 25000, exact

    int start = rowp[node];
    int end   = rowp[node + 1];

    float acc0 = bf2f(emb_in[(size_t)node * D + lane]);   // self term
    float acc1 = 0.f;

    for (int base = start; base < end; base += 8) {
        int nb = end - base; if (nb > 8) nb = 8;          // wave-uniform
        int off = lane & 7; if (off >= nb) off = 0;       // clamp tail reads
        int idx = col[base + off];                        // lanes 0..7 matter
#pragma unroll
        for (int r = 0; r < 8; ++r) {
            if (r < nb) {                                 // uniform -> s_cbranch
                int src = __shfl(idx, r, 64);             // v_readlane_b32
                float v = bf2f(emb_in[(size_t)src * D + lane]);
                if (r & 1) acc1 += v; else acc0 += v;
            }
        }
    }
    x_out[(size_t)node * D + lane] = acc0 + acc1;         // 256 B coalesced
}

// ---------------------------------------------------------------------------
// Tiled conv GEMM: y = relu(x @ W^T + b) for a 64-node tile.
// X-tile and W both staged in LDS (stride 68 floats -> all inner-loop b128
// reads are <=2-way bank aliased = free). Thread (i=t&15, j=t>>4) computes a
// STRIDED 4x4 microtile: nodes i+16di, dims j+16dj. No W-in-VGPR residency
// needed. !SCORE: emit bf16 embeds (LDS transpose for coalescing).
// SCORE: reuse Xs for fp32 y, per-node in-LDS dot vs pattern -> score_out.
template <bool SCORE>
__global__ __launch_bounds__(256) void conv_tile_kernel(
        const float* __restrict__ x,
        const float* __restrict__ W,
        const float* __restrict__ b,
        const float* __restrict__ pattern_emb,
        const int* __restrict__ pattern_id,
        unsigned short* __restrict__ emb_out,
        float* __restrict__ score_out) {
    __shared__ float Xs[CT][XS];
    __shared__ float Wsh[D][XS];
    __shared__ unsigned short Os[CT][OS];
    __shared__ float ps[D];

    int t = threadIdx.x;
    int base = blockIdx.x * CT;
    int i = t & 15;           // node sub-index
    int j = t >> 4;           // dim sub-index

    float bj[4];
#pragma unroll
    for (int dj = 0; dj < 4; ++dj) bj[dj] = b[j + 16 * dj];

    // stage W (16 KB) and X tile (16 KB)
    {
        int c = t & 15;
        int r0 = t >> 4;
#pragma unroll
        for (int p4 = 0; p4 < 4; ++p4) {
            int r = r0 + p4 * 16;
            float4 wv4 = ((const float4*)(W + (size_t)r * D))[c];
            *((float4*)&Wsh[r][4 * c]) = wv4;
            int node = base + r;
            int nc = node < N_NODES ? node : (N_NODES - 1);
            float4 xv4 = ((const float4*)(x + (size_t)nc * D))[c];
            *((float4*)&Xs[r][4 * c]) = xv4;
        }
    }
    if (SCORE && t < D) ps[t] = pattern_emb[(size_t)pattern_id[0] * D + t];
    __syncthreads();

    float acc[4][4] = {};
    for (int k4 = 0; k4 < 16; ++k4) {
        float4 xr[4], wr[4];
#pragma unroll
        for (int di = 0; di < 4; ++di) xr[di] = *((const float4*)&Xs[i + 16 * di][4 * k4]);
#pragma unroll
        for (int dj = 0; dj < 4; ++dj) wr[dj] = *((const float4*)&Wsh[j + 16 * dj][4 * k4]);
#pragma unroll
        for (int di = 0; di < 4; ++di)
#pragma unroll
            for (int dj = 0; dj < 4; ++dj)
                acc[di][dj] += xr[di].x * wr[dj].x + xr[di].y * wr[dj].y
                             + xr[di].z * wr[dj].z + xr[di].w * wr[dj].w;
    }

    if (!SCORE) {
#pragma unroll
        for (int di = 0; di < 4; ++di)
#pragma unroll
            for (int dj = 0; dj < 4; ++dj)
                Os[i + 16 * di][j + 16 * dj] = f2bf(fmaxf(acc[di][dj] + bj[dj], 0.f));
        __syncthreads();
#pragma unroll
        for (int q = 0; q < 2; ++q) {
            int idx = t + q * 256;            // 0..511: 64 rows x 8 uint4 segs
            int r = idx >> 3, seg = idx & 7;
            int node = base + r;
            if (node < N_NODES)
                ((uint4*)(emb_out + (size_t)node * D))[seg] = *((const uint4*)&Os[r][8 * seg]);
        }
    } else {
        __syncthreads();                       // all waves done reading Xs
#pragma unroll
        for (int di = 0; di < 4; ++di)
#pragma unroll
            for (int dj = 0; dj < 4; ++dj)
                Xs[i + 16 * di][j + 16 * dj] = fmaxf(acc[di][dj] + bj[dj], 0.f);
        __syncthreads();
        if (t < CT) {                          // wave 0: one lane per node
            float dot = 0.f, n2 = 0.f, pn = 0.f;
#pragma unroll 8
            for (int k = 0; k < D; ++k) {
                float yk = Xs[t][k];
                float pk = ps[k];
                dot += yk * pk; n2 += yk * yk; pn += pk * pk;
            }
            int node = base + t;
            if (node < N_NODES)
                score_out[node] = dot / (fmaxf(sqrtf(n2), 1e-8f) * fmaxf(sqrtf(pn), 1e-8f));
        }
    }
}

// ---------------------------------------------------------------------------
// Fallback path (atomic scatter, full fp32) if ws too small for CSR arrays.
__global__ void init_embeds_kernel(const int* __restrict__ nodes,
                                   const float* __restrict__ features,
                                   const float* __restrict__ node_emb,
                                   const float* __restrict__ feat_W,
                                   const float* __restrict__ feat_b,
                                   float* __restrict__ embeds) {
    int tid = blockIdx.x * blockDim.x + threadIdx.x;
    if (tid >= N_NODES * D) return;
    int node = tid >> 6;
    int d = tid & 63;
    float acc = feat_b[d];
    const float* f = features + (size_t)node * 10;
    const float* w = feat_W + (size_t)d * 10;
#pragma unroll
    for (int j = 0; j < 10; ++j) acc += f[j] * w[j];
    embeds[tid] = node_emb[(size_t)nodes[node] * D + d] + acc;
}

__global__ void scatter_add_kernel(const int* __restrict__ edges,
                                   const float* __restrict__ embeds,
                                   float* __restrict__ agg) {
    int tid = blockIdx.x * blockDim.x + threadIdx.x;
    int edge = tid >> 6;
    int lane = tid & 63;
    if (edge >= N_EDGES) return;
    int src = edges[2 * edge + 0];
    int dst = edges[2 * edge + 1];
    atomicAdd(&agg[(size_t)dst * D + lane], embeds[(size_t)src * D + lane]);
}

__global__ void conv_inplace_kernel(const float* __restrict__ agg,
                                    const float* __restrict__ W,
                                    const float* __restrict__ b,
                                    float* __restrict__ embeds) {
    __shared__ float Ws[D * 65];
    __shared__ float xs[4][D];
    for (int i = threadIdx.x; i < D * D; i += blockDim.x) {
        int d = i >> 6, k = i & 63;
        Ws[d * 65 + k] = W[i];
    }
    __syncthreads();
    int lane_d = threadIdx.x & 63;
    int local_n = threadIdx.x >> 6;
    float bias = b[lane_d];
    const int n_chunks = (N_NODES + 3) / 4;
    for (int chunk = blockIdx.x; chunk < n_chunks; chunk += gridDim.x) {
        int node = chunk * 4 + local_n;
        if (node < N_NODES) {
            size_t base = (size_t)node * D + lane_d;
            xs[local_n][lane_d] = embeds[base] + agg[base];
        }
        __syncthreads();
        if (node < N_NODES) {
            float acc = bias;
#pragma unroll
            for (int k = 0; k < D; ++k) acc += xs[local_n][k] * Ws[lane_d * 65 + k];
            embeds[(size_t)node * D + lane_d] = fmaxf(acc, 0.0f);
        }
        __syncthreads();
    }
}

__global__ void final_score_kernel(const float* __restrict__ embeds,
                                   const float* __restrict__ pattern_emb,
                                   const int* __restrict__ pattern_id,
                                   float* __restrict__ out) {
    int lane = threadIdx.x & 63;
    int wave = threadIdx.x >> 6;
    int node = blockIdx.x * 4 + wave;
    int pid = pattern_id[0];
    float p = pattern_emb[(size_t)pid * D + lane];
    float pn = p * p;
#pragma unroll
    for (int m = 32; m > 0; m >>= 1) pn += __shfl_xor(pn, m, 64);
    if (node < N_NODES) {
        float e = embeds[(size_t)node * D + lane];
        float dot = e * p;
        float n2 = e * e;
#pragma unroll
        for (int m = 32; m > 0; m >>= 1) {
            dot += __shfl_xor(dot, m, 64);
            n2  += __shfl_xor(n2, m, 64);
        }
        if (lane == 0) {
            float denom = fmaxf(sqrtf(n2), 1e-8f) * fmaxf(sqrtf(pn), 1e-8f);
            out[node] = dot / denom;
        }
    }
}

// ---------------------------------------------------------------------------
extern "C" void kernel_launch(void* const* d_in, const int* in_sizes, int n_in,
                              void* d_out, int out_size, void* d_ws, size_t ws_size,
                              hipStream_t stream) {
    const int*   nodes       = (const int*)d_in[0];
    const int*   edges       = (const int*)d_in[1];
    const float* features    = (const float*)d_in[2];
    const float* node_emb    = (const float*)d_in[3];
    const float* feat_W      = (const float*)d_in[4];
    const float* feat_b      = (const float*)d_in[5];
    const float* conv1_W     = (const float*)d_in[6];
    const float* conv1_b     = (const float*)d_in[7];
    const float* pattern_emb = (const float*)d_in[8];
    const int*   pattern_id  = (const int*)d_in[9];
    float* out = (float*)d_out;

    const size_t emb_f32_bytes = (size_t)N_NODES * D * sizeof(float);   // 25.6 MB
    const size_t emb_bf_bytes  = (size_t)N_NODES * D * 2;               // 12.8 MB
    auto align256 = [](size_t x) { return (x + 255) & ~(size_t)255; };

    size_t o_embA = 0;
    size_t o_embB = o_embA + align256(emb_bf_bytes);
    size_t o_xbuf = o_embB + align256(emb_bf_bytes);
    size_t o_col  = o_xbuf + align256(emb_f32_bytes);
    size_t o_rank = o_col  + align256((size_t)N_EDGES * 4);
    size_t o_row  = o_rank + align256((size_t)N_EDGES * 4);
    size_t o_deg  = o_row  + align256((size_t)(N_NODES + 1) * 4);
    size_t o_bsum = o_deg  + align256((size_t)N_NODES * 4);
    size_t o_boff = o_bsum + align256((size_t)NB1 * 4);
    size_t need   = o_boff + align256((size_t)NB1 * 4);

    char* ws = (char*)d_ws;

    if (ws_size >= need) {
        unsigned short* embA = (unsigned short*)(ws + o_embA);
        unsigned short* embB = (unsigned short*)(ws + o_embB);
        float* xbuf = (float*)(ws + o_xbuf);
        int*   col  = (int*)(ws + o_col);
        int*   rank = (int*)(ws + o_rank);
        int*   rowp = (int*)(ws + o_row);
        int*   deg  = (int*)(ws + o_deg);
        int*   bsum = (int*)(ws + o_bsum);

        hipMemsetAsync(deg, 0, (size_t)N_NODES * 4, stream);
        hist_rank_kernel<<<FILL_BLOCKS, 256, 0, stream>>>((const int2*)edges, deg, rank);
        scan1_kernel<<<NB1, SCAN_B, 0, stream>>>(deg, rowp, bsum);
        scan23_kernel<<<NB1, SCAN_B, 0, stream>>>(rowp, bsum);
        fill_init_kernel<<<FILL_BLOCKS + INIT_BLOCKS, 256, 0, stream>>>(
            (const int2*)edges, rank, rowp, col,
            nodes, features, node_emb, feat_W, feat_b, embA);

        const int conv_grid = (N_NODES + CT - 1) / CT;   // 1563

        // iter 1: gather(bf16->fp32) + tiled conv -> embB (bf16)
        gather_x_kernel<<<N_NODES / 4, 256, 0, stream>>>(embA, rowp, col, xbuf);
        conv_tile_kernel<false><<<conv_grid, 256, 0, stream>>>(
            xbuf, conv1_W, conv1_b, pattern_emb, pattern_id, embB, nullptr);
        // iter 2: gather + tiled conv fused with cosine score -> out
        gather_x_kernel<<<N_NODES / 4, 256, 0, stream>>>(embB, rowp, col, xbuf);
        conv_tile_kernel<true><<<conv_grid, 256, 0, stream>>>(
            xbuf, conv1_W, conv1_b, pattern_emb, pattern_id, nullptr, out);
    } else {
        float* embeds = (float*)ws;
        float* agg = (float*)(ws + align256(emb_f32_bytes));
        init_embeds_kernel<<<(N_NODES * D + 255) / 256, 256, 0, stream>>>(
            nodes, features, node_emb, feat_W, feat_b, embeds);
        for (int it = 0; it < 2; ++it) {
            hipMemsetAsync(agg, 0, emb_f32_bytes, stream);
            long long total = (long long)N_EDGES * 64;
            scatter_add_kernel<<<(int)((total + 255) / 256), 256, 0, stream>>>(edges, embeds, agg);
            conv_inplace_kernel<<<2048, 256, 0, stream>>>(agg, conv1_W, conv1_b, embeds);
        }
        final_score_kernel<<<(N_NODES + 3) / 4, 256, 0, stream>>>(
            embeds, pattern_emb, pattern_id, out);
    }
}

// Round 11
// 272.196 us; speedup vs baseline: 1.1389x; 1.1389x over previous
//
#include <hip/hip_runtime.h>
#include <hip/hip_bf16.h>

#define N_NODES 100000
#define N_EDGES 800000
#define D 64
#define SCAN_B 256
#define NB1 ((N_NODES + SCAN_B - 1) / SCAN_B)   // 391 blocks
#define FILL_BLOCKS (N_EDGES / 256)             // 3125, exact
#define INIT_BLOCKS (N_NODES * D / 256)         // 25000, exact
#define CT 64                                   // conv tile: nodes per block
#define XS 68                                   // fp32 LDS row stride (bank-safe)
#define OS 72                                   // u16 LDS out row stride

// bf16 helpers: storage-only bf16 (embeds); all math in fp32.
__device__ __forceinline__ unsigned short f2bf(float f) {
    union { float f; unsigned u; } v; v.f = f;
    unsigned r = v.u + 0x7fffu + ((v.u >> 16) & 1u);   // round-to-nearest-even
    return (unsigned short)(r >> 16);
}
__device__ __forceinline__ float bf2f(unsigned short u) {
    return __uint_as_float(((unsigned)u) << 16);
}

// ---------------------------------------------------------------------------
// hist + rank: deg[dst]++, rank[e] = arrival order of edge e at its dst.
__global__ __launch_bounds__(256) void hist_rank_kernel(
        const int2* __restrict__ edges,
        int* __restrict__ deg,
        int* __restrict__ rank) {
    int t = blockIdx.x * 256 + threadIdx.x;
    int2 e = edges[t];                      // grid exact: 3125*256 == N_EDGES
    rank[t] = atomicAdd(&deg[e.y], 1);
}

// ---------------------------------------------------------------------------
// scan1: block-local exclusive scan over deg -> row_ptr, emit block totals.
__global__ void scan1_kernel(const int* __restrict__ deg,
                             int* __restrict__ row_ptr,
                             int* __restrict__ bsum) {
    __shared__ int tmp[SCAN_B];
    int t = threadIdx.x;
    int i = blockIdx.x * SCAN_B + t;
    int v = (i < N_NODES) ? deg[i] : 0;
    tmp[t] = v;
    __syncthreads();
#pragma unroll
    for (int off = 1; off < SCAN_B; off <<= 1) {
        int a = (t >= off) ? tmp[t - off] : 0;
        __syncthreads();
        tmp[t] += a;
        __syncthreads();
    }
    if (i < N_NODES) row_ptr[i] = tmp[t] - v;   // exclusive
    if (t == SCAN_B - 1) bsum[blockIdx.x] = tmp[t];
}

// scan2+scan3 merged: each block reduce-sums bsum[0..blockIdx-1] (391 ints)
// and adds it to its 256 row_ptr entries.
__global__ void scan23_kernel(int* __restrict__ row_ptr,
                              const int* __restrict__ bsum) {
    __shared__ int red[SCAN_B];
    int t = threadIdx.x;
    int partial = 0;
    if (t < blockIdx.x && t < NB1) partial += bsum[t];
    int t2 = t + 256;
    if (t2 < blockIdx.x && t2 < NB1) partial += bsum[t2];
    red[t] = partial;
    __syncthreads();
#pragma unroll
    for (int off = 128; off > 0; off >>= 1) {
        if (t < off) red[t] += red[t + off];
        __syncthreads();
    }
    int boff = red[0];
    int i = blockIdx.x * SCAN_B + t;
    if (i < N_NODES) row_ptr[i] += boff;
    if (i == 0) row_ptr[N_NODES] = N_EDGES;
}

// ---------------------------------------------------------------------------
// Fused dispatch: blocks [0, FILL_BLOCKS) scatter CSR cols (atomic-free via
// rank); blocks [FILL_BLOCKS, +INIT_BLOCKS) compute initial embeddings (bf16).
__global__ __launch_bounds__(256) void fill_init_kernel(
        const int2* __restrict__ edges,
        const int* __restrict__ rank,
        const int* __restrict__ rowp,
        int* __restrict__ col,
        const int* __restrict__ nodes,
        const float* __restrict__ features,
        const float* __restrict__ node_emb,
        const float* __restrict__ feat_W,
        const float* __restrict__ feat_b,
        unsigned short* __restrict__ embeds) {
    if (blockIdx.x < FILL_BLOCKS) {
        int t = blockIdx.x * 256 + threadIdx.x;
        int2 e = edges[t];
        col[rowp[e.y] + rank[t]] = e.x;
    } else {
        int tid = (blockIdx.x - FILL_BLOCKS) * 256 + threadIdx.x;
        int node = tid >> 6;
        int d = tid & 63;
        float acc = feat_b[d];
        const float* f = features + (size_t)node * 10;
        const float* w = feat_W + (size_t)d * 10;
#pragma unroll
        for (int j = 0; j < 10; ++j) acc += f[j] * w[j];
        embeds[tid] = f2bf(node_emb[(size_t)nodes[node] * D + d] + acc);
    }
}

// ---------------------------------------------------------------------------
// x[node] = emb_in[node] + sum_{src} emb_in[src]   (emb bf16, acc fp32)
// Shuffle-free: one wave per node, lane = dim (each src row = one coalesced
// 128-B u16 load across 64 lanes; accumulation purely per-lane).
// MLP: full 8-edge chunks are BRANCH-FREE straight-line code -> 8 independent
// loads in flight before the first s_waitcnt (round-10's per-r uniform
// branches serialized to 1 in flight: VGPR_Count 8, 61.8 us, latency-bound).
// Tail (<=7, wave-uniform) predicated once per node.
__global__ __launch_bounds__(256) void gather_x_kernel(
        const unsigned short* __restrict__ emb_in,
        const int* __restrict__ rowp,
        const int* __restrict__ col,
        float* __restrict__ x_out) {
    int lane = threadIdx.x & 63;
    int wv   = threadIdx.x >> 6;
    int node = blockIdx.x * 4 + wv;          // grid = 25000, exact

    int start = rowp[node];
    int end   = rowp[node + 1];

    float acc0 = bf2f(emb_in[(size_t)node * D + lane]);   // self term
    float acc1 = 0.f, acc2 = 0.f, acc3 = 0.f;

    int base = start;
    for (; base + 8 <= end; base += 8) {                  // full chunks: no branches
        int idx = col[base + (lane & 7)];
        int s0 = __shfl(idx, 0, 64), s1 = __shfl(idx, 1, 64);
        int s2 = __shfl(idx, 2, 64), s3 = __shfl(idx, 3, 64);
        int s4 = __shfl(idx, 4, 64), s5 = __shfl(idx, 5, 64);
        int s6 = __shfl(idx, 6, 64), s7 = __shfl(idx, 7, 64);
        float v0 = bf2f(emb_in[(size_t)s0 * D + lane]);
        float v1 = bf2f(emb_in[(size_t)s1 * D + lane]);
        float v2 = bf2f(emb_in[(size_t)s2 * D + lane]);
        float v3 = bf2f(emb_in[(size_t)s3 * D + lane]);
        float v4 = bf2f(emb_in[(size_t)s4 * D + lane]);
        float v5 = bf2f(emb_in[(size_t)s5 * D + lane]);
        float v6 = bf2f(emb_in[(size_t)s6 * D + lane]);
        float v7 = bf2f(emb_in[(size_t)s7 * D + lane]);
        acc0 += v0 + v4; acc1 += v1 + v5;
        acc2 += v2 + v6; acc3 += v3 + v7;
    }

    int rem = end - base;                                 // 0..7, wave-uniform
    if (rem) {
        int off = lane & 7; if (off >= rem) off = 0;      // clamp tail reads
        int idx = col[base + off];
#pragma unroll
        for (int r = 0; r < 7; ++r) {
            if (r < rem) {
                int src = __shfl(idx, r, 64);
                float v = bf2f(emb_in[(size_t)src * D + lane]);
                if (r & 1) acc1 += v; else acc0 += v;
            }
        }
    }
    x_out[(size_t)node * D + lane] = (acc0 + acc1) + (acc2 + acc3);
}

// ---------------------------------------------------------------------------
// Tiled conv GEMM: y = relu(x @ W^T + b) for a 64-node tile.
// X-tile and W both staged in LDS (stride 68 floats -> all inner-loop b128
// reads are <=2-way bank aliased = free). Thread (i=t&15, j=t>>4) computes a
// STRIDED 4x4 microtile: nodes i+16di, dims j+16dj. No W-in-VGPR residency
// needed. !SCORE: emit bf16 embeds (LDS transpose for coalescing).
// SCORE: reuse Xs for fp32 y, per-node in-LDS dot vs pattern -> score_out.
template <bool SCORE>
__global__ __launch_bounds__(256) void conv_tile_kernel(
        const float* __restrict__ x,
        const float* __restrict__ W,
        const float* __restrict__ b,
        const float* __restrict__ pattern_emb,
        const int* __restrict__ pattern_id,
        unsigned short* __restrict__ emb_out,
        float* __restrict__ score_out) {
    __shared__ float Xs[CT][XS];
    __shared__ float Wsh[D][XS];
    __shared__ unsigned short Os[CT][OS];
    __shared__ float ps[D];

    int t = threadIdx.x;
    int base = blockIdx.x * CT;
    int i = t & 15;           // node sub-index
    int j = t >> 4;           // dim sub-index

    float bj[4];
#pragma unroll
    for (int dj = 0; dj < 4; ++dj) bj[dj] = b[j + 16 * dj];

    // stage W (16 KB) and X tile (16 KB)
    {
        int c = t & 15;
        int r0 = t >> 4;
#pragma unroll
        for (int p4 = 0; p4 < 4; ++p4) {
            int r = r0 + p4 * 16;
            float4 wv4 = ((const float4*)(W + (size_t)r * D))[c];
            *((float4*)&Wsh[r][4 * c]) = wv4;
            int node = base + r;
            int nc = node < N_NODES ? node : (N_NODES - 1);
            float4 xv4 = ((const float4*)(x + (size_t)nc * D))[c];
            *((float4*)&Xs[r][4 * c]) = xv4;
        }
    }
    if (SCORE && t < D) ps[t] = pattern_emb[(size_t)pattern_id[0] * D + t];
    __syncthreads();

    float acc[4][4] = {};
    for (int k4 = 0; k4 < 16; ++k4) {
        float4 xr[4], wr[4];
#pragma unroll
        for (int di = 0; di < 4; ++di) xr[di] = *((const float4*)&Xs[i + 16 * di][4 * k4]);
#pragma unroll
        for (int dj = 0; dj < 4; ++dj) wr[dj] = *((const float4*)&Wsh[j + 16 * dj][4 * k4]);
#pragma unroll
        for (int di = 0; di < 4; ++di)
#pragma unroll
            for (int dj = 0; dj < 4; ++dj)
                acc[di][dj] += xr[di].x * wr[dj].x + xr[di].y * wr[dj].y
                             + xr[di].z * wr[dj].z + xr[di].w * wr[dj].w;
    }

    if (!SCORE) {
#pragma unroll
        for (int di = 0; di < 4; ++di)
#pragma unroll
            for (int dj = 0; dj < 4; ++dj)
                Os[i + 16 * di][j + 16 * dj] = f2bf(fmaxf(acc[di][dj] + bj[dj], 0.f));
        __syncthreads();
#pragma unroll
        for (int q = 0; q < 2; ++q) {
            int idx = t + q * 256;            // 0..511: 64 rows x 8 uint4 segs
            int r = idx >> 3, seg = idx & 7;
            int node = base + r;
            if (node < N_NODES)
                ((uint4*)(emb_out + (size_t)node * D))[seg] = *((const uint4*)&Os[r][8 * seg]);
        }
    } else {
        __syncthreads();                       // all waves done reading Xs
#pragma unroll
        for (int di = 0; di < 4; ++di)
#pragma unroll
            for (int dj = 0; dj < 4; ++dj)
                Xs[i + 16 * di][j + 16 * dj] = fmaxf(acc[di][dj] + bj[dj], 0.f);
        __syncthreads();
        if (t < CT) {                          // wave 0: one lane per node
            float dot = 0.f, n2 = 0.f, pn = 0.f;
#pragma unroll 8
            for (int k = 0; k < D; ++k) {
                float yk = Xs[t][k];
                float pk = ps[k];
                dot += yk * pk; n2 += yk * yk; pn += pk * pk;
            }
            int node = base + t;
            if (node < N_NODES)
                score_out[node] = dot / (fmaxf(sqrtf(n2), 1e-8f) * fmaxf(sqrtf(pn), 1e-8f));
        }
    }
}

// ---------------------------------------------------------------------------
// Fallback path (atomic scatter, full fp32) if ws too small for CSR arrays.
__global__ void init_embeds_kernel(const int* __restrict__ nodes,
                                   const float* __restrict__ features,
                                   const float* __restrict__ node_emb,
                                   const float* __restrict__ feat_W,
                                   const float* __restrict__ feat_b,
                                   float* __restrict__ embeds) {
    int tid = blockIdx.x * blockDim.x + threadIdx.x;
    if (tid >= N_NODES * D) return;
    int node = tid >> 6;
    int d = tid & 63;
    float acc = feat_b[d];
    const float* f = features + (size_t)node * 10;
    const float* w = feat_W + (size_t)d * 10;
#pragma unroll
    for (int j = 0; j < 10; ++j) acc += f[j] * w[j];
    embeds[tid] = node_emb[(size_t)nodes[node] * D + d] + acc;
}

__global__ void scatter_add_kernel(const int* __restrict__ edges,
                                   const float* __restrict__ embeds,
                                   float* __restrict__ agg) {
    int tid = blockIdx.x * blockDim.x + threadIdx.x;
    int edge = tid >> 6;
    int lane = tid & 63;
    if (edge >= N_EDGES) return;
    int src = edges[2 * edge + 0];
    int dst = edges[2 * edge + 1];
    atomicAdd(&agg[(size_t)dst * D + lane], embeds[(size_t)src * D + lane]);
}

__global__ void conv_inplace_kernel(const float* __restrict__ agg,
                                    const float* __restrict__ W,
                                    const float* __restrict__ b,
                                    float* __restrict__ embeds) {
    __shared__ float Ws[D * 65];
    __shared__ float xs[4][D];
    for (int i = threadIdx.x; i < D * D; i += blockDim.x) {
        int d = i >> 6, k = i & 63;
        Ws[d * 65 + k] = W[i];
    }
    __syncthreads();
    int lane_d = threadIdx.x & 63;
    int local_n = threadIdx.x >> 6;
    float bias = b[lane_d];
    const int n_chunks = (N_NODES + 3) / 4;
    for (int chunk = blockIdx.x; chunk < n_chunks; chunk += gridDim.x) {
        int node = chunk * 4 + local_n;
        if (node < N_NODES) {
            size_t base = (size_t)node * D + lane_d;
            xs[local_n][lane_d] = embeds[base] + agg[base];
        }
        __syncthreads();
        if (node < N_NODES) {
            float acc = bias;
#pragma unroll
            for (int k = 0; k < D; ++k) acc += xs[local_n][k] * Ws[lane_d * 65 + k];
            embeds[(size_t)node * D + lane_d] = fmaxf(acc, 0.0f);
        }
        __syncthreads();
    }
}

__global__ void final_score_kernel(const float* __restrict__ embeds,
                                   const float* __restrict__ pattern_emb,
                                   const int* __restrict__ pattern_id,
                                   float* __restrict__ out) {
    int lane = threadIdx.x & 63;
    int wave = threadIdx.x >> 6;
    int node = blockIdx.x * 4 + wave;
    int pid = pattern_id[0];
    float p = pattern_emb[(size_t)pid * D + lane];
    float pn = p * p;
#pragma unroll
    for (int m = 32; m > 0; m >>= 1) pn += __shfl_xor(pn, m, 64);
    if (node < N_NODES) {
        float e = embeds[(size_t)node * D + lane];
        float dot = e * p;
        float n2 = e * e;
#pragma unroll
        for (int m = 32; m > 0; m >>= 1) {
            dot += __shfl_xor(dot, m, 64);
            n2  += __shfl_xor(n2, m, 64);
        }
        if (lane == 0) {
            float denom = fmaxf(sqrtf(n2), 1e-8f) * fmaxf(sqrtf(pn), 1e-8f);
            out[node] = dot / denom;
        }
    }
}

// ---------------------------------------------------------------------------
extern "C" void kernel_launch(void* const* d_in, const int* in_sizes, int n_in,
                              void* d_out, int out_size, void* d_ws, size_t ws_size,
                              hipStream_t stream) {
    const int*   nodes       = (const int*)d_in[0];
    const int*   edges       = (const int*)d_in[1];
    const float* features    = (const float*)d_in[2];
    const float* node_emb    = (const float*)d_in[3];
    const float* feat_W      = (const float*)d_in[4];
    const float* feat_b      = (const float*)d_in[5];
    const float* conv1_W     = (const float*)d_in[6];
    const float* conv1_b     = (const float*)d_in[7];
    const float* pattern_emb = (const float*)d_in[8];
    const int*   pattern_id  = (const int*)d_in[9];
    float* out = (float*)d_out;

    const size_t emb_f32_bytes = (size_t)N_NODES * D * sizeof(float);   // 25.6 MB
    const size_t emb_bf_bytes  = (size_t)N_NODES * D * 2;               // 12.8 MB
    auto align256 = [](size_t x) { return (x + 255) & ~(size_t)255; };

    size_t o_embA = 0;
    size_t o_embB = o_embA + align256(emb_bf_bytes);
    size_t o_xbuf = o_embB + align256(emb_bf_bytes);
    size_t o_col  = o_xbuf + align256(emb_f32_bytes);
    size_t o_rank = o_col  + align256((size_t)N_EDGES * 4);
    size_t o_row  = o_rank + align256((size_t)N_EDGES * 4);
    size_t o_deg  = o_row  + align256((size_t)(N_NODES + 1) * 4);
    size_t o_bsum = o_deg  + align256((size_t)N_NODES * 4);
    size_t need   = o_bsum + align256((size_t)NB1 * 4);

    char* ws = (char*)d_ws;

    if (ws_size >= need) {
        unsigned short* embA = (unsigned short*)(ws + o_embA);
        unsigned short* embB = (unsigned short*)(ws + o_embB);
        float* xbuf = (float*)(ws + o_xbuf);
        int*   col  = (int*)(ws + o_col);
        int*   rank = (int*)(ws + o_rank);
        int*   rowp = (int*)(ws + o_row);
        int*   deg  = (int*)(ws + o_deg);
        int*   bsum = (int*)(ws + o_bsum);

        hipMemsetAsync(deg, 0, (size_t)N_NODES * 4, stream);
        hist_rank_kernel<<<FILL_BLOCKS, 256, 0, stream>>>((const int2*)edges, deg, rank);
        scan1_kernel<<<NB1, SCAN_B, 0, stream>>>(deg, rowp, bsum);
        scan23_kernel<<<NB1, SCAN_B, 0, stream>>>(rowp, bsum);
        fill_init_kernel<<<FILL_BLOCKS + INIT_BLOCKS, 256, 0, stream>>>(
            (const int2*)edges, rank, rowp, col,
            nodes, features, node_emb, feat_W, feat_b, embA);

        const int conv_grid = (N_NODES + CT - 1) / CT;   // 1563

        // iter 1: gather(bf16->fp32) + tiled conv -> embB (bf16)
        gather_x_kernel<<<N_NODES / 4, 256, 0, stream>>>(embA, rowp, col, xbuf);
        conv_tile_kernel<false><<<conv_grid, 256, 0, stream>>>(
            xbuf, conv1_W, conv1_b, pattern_emb, pattern_id, embB, nullptr);
        // iter 2: gather + tiled conv fused with cosine score -> out
        gather_x_kernel<<<N_NODES / 4, 256, 0, stream>>>(embB, rowp, col, xbuf);
        conv_tile_kernel<true><<<conv_grid, 256, 0, stream>>>(
            xbuf, conv1_W, conv1_b, pattern_emb, pattern_id, nullptr, out);
    } else {
        float* embeds = (float*)ws;
        float* agg = (float*)(ws + align256(emb_f32_bytes));
        init_embeds_kernel<<<(N_NODES * D + 255) / 256, 256, 0, stream>>>(
            nodes, features, node_emb, feat_W, feat_b, embeds);
        for (int it = 0; it < 2; ++it) {
            hipMemsetAsync(agg, 0, emb_f32_bytes, stream);
            long long total = (long long)N_EDGES * 64;
            scatter_add_kernel<<<(int)((total + 255) / 256), 256, 0, stream>>>(edges, embeds, agg);
            conv_inplace_kernel<<<2048, 256, 0, stream>>>(agg, conv1_W, conv1_b, embeds);
        }
        final_score_kernel<<<(N_NODES + 3) / 4, 256, 0, stream>>>(
            embeds, pattern_emb, pattern_id, out);
    }
}

// Round 12
// 257.983 us; speedup vs baseline: 1.2017x; 1.0551x over previous
//
#include <hip/hip_runtime.h>
#include <hip/hip_bf16.h>

#define N_NODES 100000
#define N_EDGES 800000
#define D 64
#define SCAN_B 256
#define NB1 ((N_NODES + SCAN_B - 1) / SCAN_B)   // 391 blocks
#define FILL_BLOCKS (N_EDGES / 256)             // 3125, exact
#define INIT_BLOCKS (N_NODES * D / 256)         // 25000, exact
#define CT 64                                   // conv tile: nodes per block
#define XS 68                                   // fp32 LDS row stride (bank-safe)
#define OS 72                                   // u16 LDS out row stride

// bf16 helpers: storage-only bf16 (embeds); all math in fp32.
__device__ __forceinline__ unsigned short f2bf(float f) {
    union { float f; unsigned u; } v; v.f = f;
    unsigned r = v.u + 0x7fffu + ((v.u >> 16) & 1u);   // round-to-nearest-even
    return (unsigned short)(r >> 16);
}
__device__ __forceinline__ float bf2f(unsigned short u) {
    return __uint_as_float(((unsigned)u) << 16);
}
__device__ __forceinline__ void acc_bf8(float acc[8], uint4 u) {
    acc[0] += __uint_as_float(u.x << 16);
    acc[1] += __uint_as_float(u.x & 0xffff0000u);
    acc[2] += __uint_as_float(u.y << 16);
    acc[3] += __uint_as_float(u.y & 0xffff0000u);
    acc[4] += __uint_as_float(u.z << 16);
    acc[5] += __uint_as_float(u.z & 0xffff0000u);
    acc[6] += __uint_as_float(u.w << 16);
    acc[7] += __uint_as_float(u.w & 0xffff0000u);
}

// ---------------------------------------------------------------------------
// hist + rank: deg[dst]++, rank[e] = arrival order of edge e at its dst.
__global__ __launch_bounds__(256) void hist_rank_kernel(
        const int2* __restrict__ edges,
        int* __restrict__ deg,
        int* __restrict__ rank) {
    int t = blockIdx.x * 256 + threadIdx.x;
    int2 e = edges[t];                      // grid exact: 3125*256 == N_EDGES
    rank[t] = atomicAdd(&deg[e.y], 1);
}

// ---------------------------------------------------------------------------
// scan1: block-local exclusive scan over deg -> row_ptr, emit block totals.
__global__ void scan1_kernel(const int* __restrict__ deg,
                             int* __restrict__ row_ptr,
                             int* __restrict__ bsum) {
    __shared__ int tmp[SCAN_B];
    int t = threadIdx.x;
    int i = blockIdx.x * SCAN_B + t;
    int v = (i < N_NODES) ? deg[i] : 0;
    tmp[t] = v;
    __syncthreads();
#pragma unroll
    for (int off = 1; off < SCAN_B; off <<= 1) {
        int a = (t >= off) ? tmp[t - off] : 0;
        __syncthreads();
        tmp[t] += a;
        __syncthreads();
    }
    if (i < N_NODES) row_ptr[i] = tmp[t] - v;   // exclusive
    if (t == SCAN_B - 1) bsum[blockIdx.x] = tmp[t];
}

// scan2+scan3 merged: each block reduce-sums bsum[0..blockIdx-1] (391 ints)
// and adds it to its 256 row_ptr entries.
__global__ void scan23_kernel(int* __restrict__ row_ptr,
                              const int* __restrict__ bsum) {
    __shared__ int red[SCAN_B];
    int t = threadIdx.x;
    int partial = 0;
    if (t < blockIdx.x && t < NB1) partial += bsum[t];
    int t2 = t + 256;
    if (t2 < blockIdx.x && t2 < NB1) partial += bsum[t2];
    red[t] = partial;
    __syncthreads();
#pragma unroll
    for (int off = 128; off > 0; off >>= 1) {
        if (t < off) red[t] += red[t + off];
        __syncthreads();
    }
    int boff = red[0];
    int i = blockIdx.x * SCAN_B + t;
    if (i < N_NODES) row_ptr[i] += boff;
    if (i == 0) row_ptr[N_NODES] = N_EDGES;
}

// ---------------------------------------------------------------------------
// Fused dispatch: blocks [0, FILL_BLOCKS) scatter CSR cols (atomic-free via
// rank); blocks [FILL_BLOCKS, +INIT_BLOCKS) compute initial embeddings (bf16).
__global__ __launch_bounds__(256) void fill_init_kernel(
        const int2* __restrict__ edges,
        const int* __restrict__ rank,
        const int* __restrict__ rowp,
        int* __restrict__ col,
        const int* __restrict__ nodes,
        const float* __restrict__ features,
        const float* __restrict__ node_emb,
        const float* __restrict__ feat_W,
        const float* __restrict__ feat_b,
        unsigned short* __restrict__ embeds) {
    if (blockIdx.x < FILL_BLOCKS) {
        int t = blockIdx.x * 256 + threadIdx.x;
        int2 e = edges[t];
        col[rowp[e.y] + rank[t]] = e.x;
    } else {
        int tid = (blockIdx.x - FILL_BLOCKS) * 256 + threadIdx.x;
        int node = tid >> 6;
        int d = tid & 63;
        float acc = feat_b[d];
        const float* f = features + (size_t)node * 10;
        const float* w = feat_W + (size_t)d * 10;
#pragma unroll
        for (int j = 0; j < 10; ++j) acc += f[j] * w[j];
        embeds[tid] = f2bf(node_emb[(size_t)nodes[node] * D + d] + acc);
    }
}

// ---------------------------------------------------------------------------
// x[node] = emb_in[node] + sum_{src} emb_in[src]   (emb bf16, acc fp32)
// One WAVE per node (uniform trips). 8 groups x 8 lanes: group g loads the
// row of src (r*8+g) as uint4 (8 bf16 = 16 B/lane, 128 B/row coalesced) —
// ONE load instruction covers 8 different rows (1 KB in flight). 32-edge
// chunks, 4 static rounds: 8 independent rows in flight per wave. This is the
// best-measured gather (r9: total 259.7); the lane=dim variants (r10/r11)
// issue 8x more VMEM instructions and measured slower.
__global__ __launch_bounds__(256, 6) void gather_x_kernel(
        const unsigned short* __restrict__ emb_in,
        const int* __restrict__ rowp,
        const int* __restrict__ col,
        float* __restrict__ x_out) {
    int lane = threadIdx.x & 63;
    int wv   = threadIdx.x >> 6;
    int node = blockIdx.x * 4 + wv;          // grid = 25000, exact
    int g = lane >> 3;                        // row-group 0..7
    int c = lane & 7;                         // uint4 chunk 0..7

    int start = rowp[node];
    int end   = rowp[node + 1];

    float acc[8];
#pragma unroll
    for (int j = 0; j < 8; ++j) acc[j] = 0.f;
    if (g == 0) {                             // self term, counted once
        uint4 u = ((const uint4*)(emb_in + (size_t)node * D))[c];
        acc_bf8(acc, u);
    }

    for (int base = start; base < end; base += 32) {
        int nb = end - base; if (nb > 32) nb = 32;
        int idx = (lane < nb) ? col[base + lane] : 0;   // lanes 0..31, coalesced
#pragma unroll
        for (int r = 0; r < 4; ++r) {
            int s = r * 8 + g;                          // 0..31
            int src = __shfl(idx, s, 64);               // all lanes active
            if (s < nb) {                               // per-lane predication
                uint4 u = ((const uint4*)(emb_in + (size_t)src * D))[c];
                acc_bf8(acc, u);
            }
        }
    }

    // combine the 8 group partials (xor 8, 16, 32)
#pragma unroll
    for (int m = 8; m <= 32; m <<= 1) {
#pragma unroll
        for (int j = 0; j < 8; ++j) acc[j] += __shfl_xor(acc[j], m, 64);
    }

    if (g == 0) {                             // 8 lanes x 32 B = 256 B fp32 row
        float4 a0 = make_float4(acc[0], acc[1], acc[2], acc[3]);
        float4 a1 = make_float4(acc[4], acc[5], acc[6], acc[7]);
        float4* o = (float4*)(x_out + (size_t)node * D);
        o[2 * c]     = a0;
        o[2 * c + 1] = a1;
    }
}

// ---------------------------------------------------------------------------
// Tiled conv GEMM: y = relu(x @ W^T + b) for a 64-node tile.
// X-tile and W both staged in LDS (stride 68 floats -> all inner-loop b128
// reads are <=2-way bank aliased = free). Thread (i=t&15, j=t>>4) computes a
// STRIDED 4x4 microtile: nodes i+16di, dims j+16dj. No W-in-VGPR residency
// needed. !SCORE: emit bf16 embeds (LDS transpose for coalescing).
// SCORE: reuse Xs for fp32 y, per-node in-LDS dot vs pattern -> score_out.
template <bool SCORE>
__global__ __launch_bounds__(256) void conv_tile_kernel(
        const float* __restrict__ x,
        const float* __restrict__ W,
        const float* __restrict__ b,
        const float* __restrict__ pattern_emb,
        const int* __restrict__ pattern_id,
        unsigned short* __restrict__ emb_out,
        float* __restrict__ score_out) {
    __shared__ float Xs[CT][XS];
    __shared__ float Wsh[D][XS];
    __shared__ unsigned short Os[CT][OS];
    __shared__ float ps[D];

    int t = threadIdx.x;
    int base = blockIdx.x * CT;
    int i = t & 15;           // node sub-index
    int j = t >> 4;           // dim sub-index

    float bj[4];
#pragma unroll
    for (int dj = 0; dj < 4; ++dj) bj[dj] = b[j + 16 * dj];

    // stage W (16 KB) and X tile (16 KB)
    {
        int c = t & 15;
        int r0 = t >> 4;
#pragma unroll
        for (int p4 = 0; p4 < 4; ++p4) {
            int r = r0 + p4 * 16;
            float4 wv4 = ((const float4*)(W + (size_t)r * D))[c];
            *((float4*)&Wsh[r][4 * c]) = wv4;
            int node = base + r;
            int nc = node < N_NODES ? node : (N_NODES - 1);
            float4 xv4 = ((const float4*)(x + (size_t)nc * D))[c];
            *((float4*)&Xs[r][4 * c]) = xv4;
        }
    }
    if (SCORE && t < D) ps[t] = pattern_emb[(size_t)pattern_id[0] * D + t];
    __syncthreads();

    float acc[4][4] = {};
    for (int k4 = 0; k4 < 16; ++k4) {
        float4 xr[4], wr[4];
#pragma unroll
        for (int di = 0; di < 4; ++di) xr[di] = *((const float4*)&Xs[i + 16 * di][4 * k4]);
#pragma unroll
        for (int dj = 0; dj < 4; ++dj) wr[dj] = *((const float4*)&Wsh[j + 16 * dj][4 * k4]);
#pragma unroll
        for (int di = 0; di < 4; ++di)
#pragma unroll
            for (int dj = 0; dj < 4; ++dj)
                acc[di][dj] += xr[di].x * wr[dj].x + xr[di].y * wr[dj].y
                             + xr[di].z * wr[dj].z + xr[di].w * wr[dj].w;
    }

    if (!SCORE) {
#pragma unroll
        for (int di = 0; di < 4; ++di)
#pragma unroll
            for (int dj = 0; dj < 4; ++dj)
                Os[i + 16 * di][j + 16 * dj] = f2bf(fmaxf(acc[di][dj] + bj[dj], 0.f));
        __syncthreads();
#pragma unroll
        for (int q = 0; q < 2; ++q) {
            int idx = t + q * 256;            // 0..511: 64 rows x 8 uint4 segs
            int r = idx >> 3, seg = idx & 7;
            int node = base + r;
            if (node < N_NODES)
                ((uint4*)(emb_out + (size_t)node * D))[seg] = *((const uint4*)&Os[r][8 * seg]);
        }
    } else {
        __syncthreads();                       // all waves done reading Xs
#pragma unroll
        for (int di = 0; di < 4; ++di)
#pragma unroll
            for (int dj = 0; dj < 4; ++dj)
                Xs[i + 16 * di][j + 16 * dj] = fmaxf(acc[di][dj] + bj[dj], 0.f);
        __syncthreads();
        if (t < CT) {                          // wave 0: one lane per node
            float dot = 0.f, n2 = 0.f, pn = 0.f;
#pragma unroll 8
            for (int k = 0; k < D; ++k) {
                float yk = Xs[t][k];
                float pk = ps[k];
                dot += yk * pk; n2 += yk * yk; pn += pk * pk;
            }
            int node = base + t;
            if (node < N_NODES)
                score_out[node] = dot / (fmaxf(sqrtf(n2), 1e-8f) * fmaxf(sqrtf(pn), 1e-8f));
        }
    }
}

// ---------------------------------------------------------------------------
// Fallback path (atomic scatter, full fp32) if ws too small for CSR arrays.
__global__ void init_embeds_kernel(const int* __restrict__ nodes,
                                   const float* __restrict__ features,
                                   const float* __restrict__ node_emb,
                                   const float* __restrict__ feat_W,
                                   const float* __restrict__ feat_b,
                                   float* __restrict__ embeds) {
    int tid = blockIdx.x * blockDim.x + threadIdx.x;
    if (tid >= N_NODES * D) return;
    int node = tid >> 6;
    int d = tid & 63;
    float acc = feat_b[d];
    const float* f = features + (size_t)node * 10;
    const float* w = feat_W + (size_t)d * 10;
#pragma unroll
    for (int j = 0; j < 10; ++j) acc += f[j] * w[j];
    embeds[tid] = node_emb[(size_t)nodes[node] * D + d] + acc;
}

__global__ void scatter_add_kernel(const int* __restrict__ edges,
                                   const float* __restrict__ embeds,
                                   float* __restrict__ agg) {
    int tid = blockIdx.x * blockDim.x + threadIdx.x;
    int edge = tid >> 6;
    int lane = tid & 63;
    if (edge >= N_EDGES) return;
    int src = edges[2 * edge + 0];
    int dst = edges[2 * edge + 1];
    atomicAdd(&agg[(size_t)dst * D + lane], embeds[(size_t)src * D + lane]);
}

__global__ void conv_inplace_kernel(const float* __restrict__ agg,
                                    const float* __restrict__ W,
                                    const float* __restrict__ b,
                                    float* __restrict__ embeds) {
    __shared__ float Ws[D * 65];
    __shared__ float xs[4][D];
    for (int i = threadIdx.x; i < D * D; i += blockDim.x) {
        int d = i >> 6, k = i & 63;
        Ws[d * 65 + k] = W[i];
    }
    __syncthreads();
    int lane_d = threadIdx.x & 63;
    int local_n = threadIdx.x >> 6;
    float bias = b[lane_d];
    const int n_chunks = (N_NODES + 3) / 4;
    for (int chunk = blockIdx.x; chunk < n_chunks; chunk += gridDim.x) {
        int node = chunk * 4 + local_n;
        if (node < N_NODES) {
            size_t base = (size_t)node * D + lane_d;
            xs[local_n][lane_d] = embeds[base] + agg[base];
        }
        __syncthreads();
        if (node < N_NODES) {
            float acc = bias;
#pragma unroll
            for (int k = 0; k < D; ++k) acc += xs[local_n][k] * Ws[lane_d * 65 + k];
            embeds[(size_t)node * D + lane_d] = fmaxf(acc, 0.0f);
        }
        __syncthreads();
    }
}

__global__ void final_score_kernel(const float* __restrict__ embeds,
                                   const float* __restrict__ pattern_emb,
                                   const int* __restrict__ pattern_id,
                                   float* __restrict__ out) {
    int lane = threadIdx.x & 63;
    int wave = threadIdx.x >> 6;
    int node = blockIdx.x * 4 + wave;
    int pid = pattern_id[0];
    float p = pattern_emb[(size_t)pid * D + lane];
    float pn = p * p;
#pragma unroll
    for (int m = 32; m > 0; m >>= 1) pn += __shfl_xor(pn, m, 64);
    if (node < N_NODES) {
        float e = embeds[(size_t)node * D + lane];
        float dot = e * p;
        float n2 = e * e;
#pragma unroll
        for (int m = 32; m > 0; m >>= 1) {
            dot += __shfl_xor(dot, m, 64);
            n2  += __shfl_xor(n2, m, 64);
        }
        if (lane == 0) {
            float denom = fmaxf(sqrtf(n2), 1e-8f) * fmaxf(sqrtf(pn), 1e-8f);
            out[node] = dot / denom;
        }
    }
}

// ---------------------------------------------------------------------------
extern "C" void kernel_launch(void* const* d_in, const int* in_sizes, int n_in,
                              void* d_out, int out_size, void* d_ws, size_t ws_size,
                              hipStream_t stream) {
    const int*   nodes       = (const int*)d_in[0];
    const int*   edges       = (const int*)d_in[1];
    const float* features    = (const float*)d_in[2];
    const float* node_emb    = (const float*)d_in[3];
    const float* feat_W      = (const float*)d_in[4];
    const float* feat_b      = (const float*)d_in[5];
    const float* conv1_W     = (const float*)d_in[6];
    const float* conv1_b     = (const float*)d_in[7];
    const float* pattern_emb = (const float*)d_in[8];
    const int*   pattern_id  = (const int*)d_in[9];
    float* out = (float*)d_out;

    const size_t emb_f32_bytes = (size_t)N_NODES * D * sizeof(float);   // 25.6 MB
    const size_t emb_bf_bytes  = (size_t)N_NODES * D * 2;               // 12.8 MB
    auto align256 = [](size_t x) { return (x + 255) & ~(size_t)255; };

    size_t o_embA = 0;
    size_t o_embB = o_embA + align256(emb_bf_bytes);
    size_t o_xbuf = o_embB + align256(emb_bf_bytes);
    size_t o_col  = o_xbuf + align256(emb_f32_bytes);
    size_t o_rank = o_col  + align256((size_t)N_EDGES * 4);
    size_t o_row  = o_rank + align256((size_t)N_EDGES * 4);
    size_t o_deg  = o_row  + align256((size_t)(N_NODES + 1) * 4);
    size_t o_bsum = o_deg  + align256((size_t)N_NODES * 4);
    size_t need   = o_bsum + align256((size_t)NB1 * 4);

    char* ws = (char*)d_ws;

    if (ws_size >= need) {
        unsigned short* embA = (unsigned short*)(ws + o_embA);
        unsigned short* embB = (unsigned short*)(ws + o_embB);
        float* xbuf = (float*)(ws + o_xbuf);
        int*   col  = (int*)(ws + o_col);
        int*   rank = (int*)(ws + o_rank);
        int*   rowp = (int*)(ws + o_row);
        int*   deg  = (int*)(ws + o_deg);
        int*   bsum = (int*)(ws + o_bsum);

        hipMemsetAsync(deg, 0, (size_t)N_NODES * 4, stream);
        hist_rank_kernel<<<FILL_BLOCKS, 256, 0, stream>>>((const int2*)edges, deg, rank);
        scan1_kernel<<<NB1, SCAN_B, 0, stream>>>(deg, rowp, bsum);
        scan23_kernel<<<NB1, SCAN_B, 0, stream>>>(rowp, bsum);
        fill_init_kernel<<<FILL_BLOCKS + INIT_BLOCKS, 256, 0, stream>>>(
            (const int2*)edges, rank, rowp, col,
            nodes, features, node_emb, feat_W, feat_b, embA);

        const int conv_grid = (N_NODES + CT - 1) / CT;   // 1563

        // iter 1: gather(bf16->fp32) + tiled conv -> embB (bf16)
        gather_x_kernel<<<N_NODES / 4, 256, 0, stream>>>(embA, rowp, col, xbuf);
        conv_tile_kernel<false><<<conv_grid, 256, 0, stream>>>(
            xbuf, conv1_W, conv1_b, pattern_emb, pattern_id, embB, nullptr);
        // iter 2: gather + tiled conv fused with cosine score -> out
        gather_x_kernel<<<N_NODES / 4, 256, 0, stream>>>(embB, rowp, col, xbuf);
        conv_tile_kernel<true><<<conv_grid, 256, 0, stream>>>(
            xbuf, conv1_W, conv1_b, pattern_emb, pattern_id, nullptr, out);
    } else {
        float* embeds = (float*)ws;
        float* agg = (float*)(ws + align256(emb_f32_bytes));
        init_embeds_kernel<<<(N_NODES * D + 255) / 256, 256, 0, stream>>>(
            nodes, features, node_emb, feat_W, feat_b, embeds);
        for (int it = 0; it < 2; ++it) {
            hipMemsetAsync(agg, 0, emb_f32_bytes, stream);
            long long total = (long long)N_EDGES * 64;
            scatter_add_kernel<<<(int)((total + 255) / 256), 256, 0, stream>>>(edges, embeds, agg);
            conv_inplace_kernel<<<2048, 256, 0, stream>>>(agg, conv1_W, conv1_b, embeds);
        }
        final_score_kernel<<<(N_NODES + 3) / 4, 256, 0, stream>>>(
            embeds, pattern_emb, pattern_id, out);
    }
}

// Round 13
// 257.215 us; speedup vs baseline: 1.2053x; 1.0030x over previous
//
#include <hip/hip_runtime.h>
#include <hip/hip_bf16.h>

#define N_NODES 100000
#define N_EDGES 800000
#define D 64
#define SCAN_B 256
#define NB1 ((N_NODES + SCAN_B - 1) / SCAN_B)   // 391 blocks
#define FILL_BLOCKS (N_EDGES / 256)             // 3125, exact
#define INIT_BLOCKS (N_NODES * D / 256)         // 25000, exact
#define CT 64                                   // conv tile: nodes per block
#define XS 68                                   // fp32 LDS row stride (bank-safe)
#define OS 72                                   // u16 LDS out row stride

// bf16 helpers: storage-only bf16 (embeds, x); all math in fp32.
__device__ __forceinline__ unsigned short f2bf(float f) {
    union { float f; unsigned u; } v; v.f = f;
    unsigned r = v.u + 0x7fffu + ((v.u >> 16) & 1u);   // round-to-nearest-even
    return (unsigned short)(r >> 16);
}
__device__ __forceinline__ float bf2f(unsigned short u) {
    return __uint_as_float(((unsigned)u) << 16);
}
__device__ __forceinline__ void acc_bf8(float acc[8], uint4 u) {
    acc[0] += __uint_as_float(u.x << 16);
    acc[1] += __uint_as_float(u.x & 0xffff0000u);
    acc[2] += __uint_as_float(u.y << 16);
    acc[3] += __uint_as_float(u.y & 0xffff0000u);
    acc[4] += __uint_as_float(u.z << 16);
    acc[5] += __uint_as_float(u.z & 0xffff0000u);
    acc[6] += __uint_as_float(u.w << 16);
    acc[7] += __uint_as_float(u.w & 0xffff0000u);
}
__device__ __forceinline__ unsigned pack2bf(float a, float b) {
    return (unsigned)f2bf(a) | ((unsigned)f2bf(b) << 16);
}

// ---------------------------------------------------------------------------
// hist + rank: deg[dst]++, rank[e] = arrival order of edge e at its dst.
__global__ __launch_bounds__(256) void hist_rank_kernel(
        const int2* __restrict__ edges,
        int* __restrict__ deg,
        int* __restrict__ rank) {
    int t = blockIdx.x * 256 + threadIdx.x;
    int2 e = edges[t];                      // grid exact: 3125*256 == N_EDGES
    rank[t] = atomicAdd(&deg[e.y], 1);
}

// ---------------------------------------------------------------------------
// scan1: block-local exclusive scan over deg -> row_ptr, emit block totals.
__global__ void scan1_kernel(const int* __restrict__ deg,
                             int* __restrict__ row_ptr,
                             int* __restrict__ bsum) {
    __shared__ int tmp[SCAN_B];
    int t = threadIdx.x;
    int i = blockIdx.x * SCAN_B + t;
    int v = (i < N_NODES) ? deg[i] : 0;
    tmp[t] = v;
    __syncthreads();
#pragma unroll
    for (int off = 1; off < SCAN_B; off <<= 1) {
        int a = (t >= off) ? tmp[t - off] : 0;
        __syncthreads();
        tmp[t] += a;
        __syncthreads();
    }
    if (i < N_NODES) row_ptr[i] = tmp[t] - v;   // exclusive
    if (t == SCAN_B - 1) bsum[blockIdx.x] = tmp[t];
}

// scan2+scan3 merged: each block reduce-sums bsum[0..blockIdx-1] (391 ints)
// and adds it to its 256 row_ptr entries.
__global__ void scan23_kernel(int* __restrict__ row_ptr,
                              const int* __restrict__ bsum) {
    __shared__ int red[SCAN_B];
    int t = threadIdx.x;
    int partial = 0;
    if (t < blockIdx.x && t < NB1) partial += bsum[t];
    int t2 = t + 256;
    if (t2 < blockIdx.x && t2 < NB1) partial += bsum[t2];
    red[t] = partial;
    __syncthreads();
#pragma unroll
    for (int off = 128; off > 0; off >>= 1) {
        if (t < off) red[t] += red[t + off];
        __syncthreads();
    }
    int boff = red[0];
    int i = blockIdx.x * SCAN_B + t;
    if (i < N_NODES) row_ptr[i] += boff;
    if (i == 0) row_ptr[N_NODES] = N_EDGES;
}

// ---------------------------------------------------------------------------
// Fused dispatch: blocks [0, FILL_BLOCKS) scatter CSR cols (atomic-free via
// rank); blocks [FILL_BLOCKS, +INIT_BLOCKS) compute initial embeddings (bf16).
__global__ __launch_bounds__(256) void fill_init_kernel(
        const int2* __restrict__ edges,
        const int* __restrict__ rank,
        const int* __restrict__ rowp,
        int* __restrict__ col,
        const int* __restrict__ nodes,
        const float* __restrict__ features,
        const float* __restrict__ node_emb,
        const float* __restrict__ feat_W,
        const float* __restrict__ feat_b,
        unsigned short* __restrict__ embeds) {
    if (blockIdx.x < FILL_BLOCKS) {
        int t = blockIdx.x * 256 + threadIdx.x;
        int2 e = edges[t];
        col[rowp[e.y] + rank[t]] = e.x;
    } else {
        int tid = (blockIdx.x - FILL_BLOCKS) * 256 + threadIdx.x;
        int node = tid >> 6;
        int d = tid & 63;
        float acc = feat_b[d];
        const float* f = features + (size_t)node * 10;
        const float* w = feat_W + (size_t)d * 10;
#pragma unroll
        for (int j = 0; j < 10; ++j) acc += f[j] * w[j];
        embeds[tid] = f2bf(node_emb[(size_t)nodes[node] * D + d] + acc);
    }
}

// ---------------------------------------------------------------------------
// x[node] = emb_in[node] + sum_{src} emb_in[src]   (emb bf16, acc fp32,
// OUTPUT bf16: halves the write + downstream conv read).
// One WAVE per node (uniform trips). 8 groups x 8 lanes: group g loads the
// row of src (r*8+g) as uint4 (8 bf16 = 16 B/lane, 128 B/row coalesced) —
// one load instruction covers 8 rows (1 KB in flight). Best-measured gather
// structure (r9/r12); launch_bounds(256,8) caps 64 VGPR -> 8 waves/SIMD
// (was 6): the gather is latency/concurrency-bound, not byte-bound.
__global__ __launch_bounds__(256, 8) void gather_x_kernel(
        const unsigned short* __restrict__ emb_in,
        const int* __restrict__ rowp,
        const int* __restrict__ col,
        unsigned short* __restrict__ x_out) {
    int lane = threadIdx.x & 63;
    int wv   = threadIdx.x >> 6;
    int node = blockIdx.x * 4 + wv;          // grid = 25000, exact
    int g = lane >> 3;                        // row-group 0..7
    int c = lane & 7;                         // uint4 chunk 0..7

    int start = rowp[node];
    int end   = rowp[node + 1];

    float acc[8];
#pragma unroll
    for (int j = 0; j < 8; ++j) acc[j] = 0.f;
    if (g == 0) {                             // self term, counted once
        uint4 u = ((const uint4*)(emb_in + (size_t)node * D))[c];
        acc_bf8(acc, u);
    }

    for (int base = start; base < end; base += 32) {
        int nb = end - base; if (nb > 32) nb = 32;
        int idx = (lane < nb) ? col[base + lane] : 0;   // lanes 0..31, coalesced
#pragma unroll
        for (int r = 0; r < 4; ++r) {
            int s = r * 8 + g;                          // 0..31
            int src = __shfl(idx, s, 64);               // all lanes active
            if (s < nb) {                               // per-lane predication
                uint4 u = ((const uint4*)(emb_in + (size_t)src * D))[c];
                acc_bf8(acc, u);
            }
        }
    }

    // combine the 8 group partials (xor 8, 16, 32)
#pragma unroll
    for (int m = 8; m <= 32; m <<= 1) {
#pragma unroll
        for (int j = 0; j < 8; ++j) acc[j] += __shfl_xor(acc[j], m, 64);
    }

    if (g == 0) {                             // 8 lanes x 16 B = 128 B bf16 row
        uint4 p;
        p.x = pack2bf(acc[0], acc[1]);
        p.y = pack2bf(acc[2], acc[3]);
        p.z = pack2bf(acc[4], acc[5]);
        p.w = pack2bf(acc[6], acc[7]);
        ((uint4*)(x_out + (size_t)node * D))[c] = p;
    }
}

// ---------------------------------------------------------------------------
// Tiled conv GEMM: y = relu(x @ W^T + b) for a 64-node tile. x is bf16,
// unpacked to fp32 LDS during staging; math fp32. X-tile and W staged in LDS
// (stride 68 floats -> inner-loop b128 reads <=2-way bank aliased = free).
// Thread (i=t&15, j=t>>4) computes a STRIDED 4x4 microtile. No W-in-VGPR
// residency needed. !SCORE: emit bf16 embeds (LDS transpose for coalescing).
// SCORE: reuse Xs for fp32 y, per-node in-LDS dot vs pattern -> score_out.
template <bool SCORE>
__global__ __launch_bounds__(256) void conv_tile_kernel(
        const unsigned short* __restrict__ x,
        const float* __restrict__ W,
        const float* __restrict__ b,
        const float* __restrict__ pattern_emb,
        const int* __restrict__ pattern_id,
        unsigned short* __restrict__ emb_out,
        float* __restrict__ score_out) {
    __shared__ float Xs[CT][XS];
    __shared__ float Wsh[D][XS];
    __shared__ unsigned short Os[CT][OS];
    __shared__ float ps[D];

    int t = threadIdx.x;
    int base = blockIdx.x * CT;
    int i = t & 15;           // node sub-index
    int j = t >> 4;           // dim sub-index

    float bj[4];
#pragma unroll
    for (int dj = 0; dj < 4; ++dj) bj[dj] = b[j + 16 * dj];

    // stage W (16 KB fp32)
    {
        int c = t & 15;
        int r0 = t >> 4;
#pragma unroll
        for (int p4 = 0; p4 < 4; ++p4) {
            int r = r0 + p4 * 16;
            float4 wv4 = ((const float4*)(W + (size_t)r * D))[c];
            *((float4*)&Wsh[r][4 * c]) = wv4;
        }
    }
    // stage X tile (8 KB bf16 -> 16 KB fp32 in LDS): 64 rows x 8 uint4 chunks
#pragma unroll
    for (int q = 0; q < 2; ++q) {
        int idx = t + q * 256;                // 0..511
        int r = idx >> 3, ck = idx & 7;
        int node = base + r;
        int nc = node < N_NODES ? node : (N_NODES - 1);
        uint4 u = ((const uint4*)(x + (size_t)nc * D))[ck];
        float4 a, bb;
        a.x  = bf2f((unsigned short)(u.x & 0xffff)); a.y  = bf2f((unsigned short)(u.x >> 16));
        a.z  = bf2f((unsigned short)(u.y & 0xffff)); a.w  = bf2f((unsigned short)(u.y >> 16));
        bb.x = bf2f((unsigned short)(u.z & 0xffff)); bb.y = bf2f((unsigned short)(u.z >> 16));
        bb.z = bf2f((unsigned short)(u.w & 0xffff)); bb.w = bf2f((unsigned short)(u.w >> 16));
        *((float4*)&Xs[r][8 * ck])     = a;
        *((float4*)&Xs[r][8 * ck + 4]) = bb;
    }
    if (SCORE && t < D) ps[t] = pattern_emb[(size_t)pattern_id[0] * D + t];
    __syncthreads();

    float acc[4][4] = {};
    for (int k4 = 0; k4 < 16; ++k4) {
        float4 xr[4], wr[4];
#pragma unroll
        for (int di = 0; di < 4; ++di) xr[di] = *((const float4*)&Xs[i + 16 * di][4 * k4]);
#pragma unroll
        for (int dj = 0; dj < 4; ++dj) wr[dj] = *((const float4*)&Wsh[j + 16 * dj][4 * k4]);
#pragma unroll
        for (int di = 0; di < 4; ++di)
#pragma unroll
            for (int dj = 0; dj < 4; ++dj)
                acc[di][dj] += xr[di].x * wr[dj].x + xr[di].y * wr[dj].y
                             + xr[di].z * wr[dj].z + xr[di].w * wr[dj].w;
    }

    if (!SCORE) {
#pragma unroll
        for (int di = 0; di < 4; ++di)
#pragma unroll
            for (int dj = 0; dj < 4; ++dj)
                Os[i + 16 * di][j + 16 * dj] = f2bf(fmaxf(acc[di][dj] + bj[dj], 0.f));
        __syncthreads();
#pragma unroll
        for (int q = 0; q < 2; ++q) {
            int idx = t + q * 256;            // 0..511: 64 rows x 8 uint4 segs
            int r = idx >> 3, seg = idx & 7;
            int node = base + r;
            if (node < N_NODES)
                ((uint4*)(emb_out + (size_t)node * D))[seg] = *((const uint4*)&Os[r][8 * seg]);
        }
    } else {
        __syncthreads();                       // all waves done reading Xs
#pragma unroll
        for (int di = 0; di < 4; ++di)
#pragma unroll
            for (int dj = 0; dj < 4; ++dj)
                Xs[i + 16 * di][j + 16 * dj] = fmaxf(acc[di][dj] + bj[dj], 0.f);
        __syncthreads();
        if (t < CT) {                          // wave 0: one lane per node
            float dot = 0.f, n2 = 0.f, pn = 0.f;
#pragma unroll 8
            for (int k = 0; k < D; ++k) {
                float yk = Xs[t][k];
                float pk = ps[k];
                dot += yk * pk; n2 += yk * yk; pn += pk * pk;
            }
            int node = base + t;
            if (node < N_NODES)
                score_out[node] = dot / (fmaxf(sqrtf(n2), 1e-8f) * fmaxf(sqrtf(pn), 1e-8f));
        }
    }
}

// ---------------------------------------------------------------------------
// Fallback path (atomic scatter, full fp32) if ws too small for CSR arrays.
__global__ void init_embeds_kernel(const int* __restrict__ nodes,
                                   const float* __restrict__ features,
                                   const float* __restrict__ node_emb,
                                   const float* __restrict__ feat_W,
                                   const float* __restrict__ feat_b,
                                   float* __restrict__ embeds) {
    int tid = blockIdx.x * blockDim.x + threadIdx.x;
    if (tid >= N_NODES * D) return;
    int node = tid >> 6;
    int d = tid & 63;
    float acc = feat_b[d];
    const float* f = features + (size_t)node * 10;
    const float* w = feat_W + (size_t)d * 10;
#pragma unroll
    for (int j = 0; j < 10; ++j) acc += f[j] * w[j];
    embeds[tid] = node_emb[(size_t)nodes[node] * D + d] + acc;
}

__global__ void scatter_add_kernel(const int* __restrict__ edges,
                                   const float* __restrict__ embeds,
                                   float* __restrict__ agg) {
    int tid = blockIdx.x * blockDim.x + threadIdx.x;
    int edge = tid >> 6;
    int lane = tid & 63;
    if (edge >= N_EDGES) return;
    int src = edges[2 * edge + 0];
    int dst = edges[2 * edge + 1];
    atomicAdd(&agg[(size_t)dst * D + lane], embeds[(size_t)src * D + lane]);
}

__global__ void conv_inplace_kernel(const float* __restrict__ agg,
                                    const float* __restrict__ W,
                                    const float* __restrict__ b,
                                    float* __restrict__ embeds) {
    __shared__ float Ws[D * 65];
    __shared__ float xs[4][D];
    for (int i = threadIdx.x; i < D * D; i += blockDim.x) {
        int d = i >> 6, k = i & 63;
        Ws[d * 65 + k] = W[i];
    }
    __syncthreads();
    int lane_d = threadIdx.x & 63;
    int local_n = threadIdx.x >> 6;
    float bias = b[lane_d];
    const int n_chunks = (N_NODES + 3) / 4;
    for (int chunk = blockIdx.x; chunk < n_chunks; chunk += gridDim.x) {
        int node = chunk * 4 + local_n;
        if (node < N_NODES) {
            size_t base = (size_t)node * D + lane_d;
            xs[local_n][lane_d] = embeds[base] + agg[base];
        }
        __syncthreads();
        if (node < N_NODES) {
            float acc = bias;
#pragma unroll
            for (int k = 0; k < D; ++k) acc += xs[local_n][k] * Ws[lane_d * 65 + k];
            embeds[(size_t)node * D + lane_d] = fmaxf(acc, 0.0f);
        }
        __syncthreads();
    }
}

__global__ void final_score_kernel(const float* __restrict__ embeds,
                                   const float* __restrict__ pattern_emb,
                                   const int* __restrict__ pattern_id,
                                   float* __restrict__ out) {
    int lane = threadIdx.x & 63;
    int wave = threadIdx.x >> 6;
    int node = blockIdx.x * 4 + wave;
    int pid = pattern_id[0];
    float p = pattern_emb[(size_t)pid * D + lane];
    float pn = p * p;
#pragma unroll
    for (int m = 32; m > 0; m >>= 1) pn += __shfl_xor(pn, m, 64);
    if (node < N_NODES) {
        float e = embeds[(size_t)node * D + lane];
        float dot = e * p;
        float n2 = e * e;
#pragma unroll
        for (int m = 32; m > 0; m >>= 1) {
            dot += __shfl_xor(dot, m, 64);
            n2  += __shfl_xor(n2, m, 64);
        }
        if (lane == 0) {
            float denom = fmaxf(sqrtf(n2), 1e-8f) * fmaxf(sqrtf(pn), 1e-8f);
            out[node] = dot / denom;
        }
    }
}

// ---------------------------------------------------------------------------
extern "C" void kernel_launch(void* const* d_in, const int* in_sizes, int n_in,
                              void* d_out, int out_size, void* d_ws, size_t ws_size,
                              hipStream_t stream) {
    const int*   nodes       = (const int*)d_in[0];
    const int*   edges       = (const int*)d_in[1];
    const float* features    = (const float*)d_in[2];
    const float* node_emb    = (const float*)d_in[3];
    const float* feat_W      = (const float*)d_in[4];
    const float* feat_b      = (const float*)d_in[5];
    const float* conv1_W     = (const float*)d_in[6];
    const float* conv1_b     = (const float*)d_in[7];
    const float* pattern_emb = (const float*)d_in[8];
    const int*   pattern_id  = (const int*)d_in[9];
    float* out = (float*)d_out;

    const size_t emb_f32_bytes = (size_t)N_NODES * D * sizeof(float);   // 25.6 MB
    const size_t emb_bf_bytes  = (size_t)N_NODES * D * 2;               // 12.8 MB
    auto align256 = [](size_t x) { return (x + 255) & ~(size_t)255; };

    size_t o_embA = 0;
    size_t o_embB = o_embA + align256(emb_bf_bytes);
    size_t o_xbuf = o_embB + align256(emb_bf_bytes);
    size_t o_col  = o_xbuf + align256(emb_bf_bytes);
    size_t o_rank = o_col  + align256((size_t)N_EDGES * 4);
    size_t o_row  = o_rank + align256((size_t)N_EDGES * 4);
    size_t o_deg  = o_row  + align256((size_t)(N_NODES + 1) * 4);
    size_t o_bsum = o_deg  + align256((size_t)N_NODES * 4);
    size_t need   = o_bsum + align256((size_t)NB1 * 4);

    char* ws = (char*)d_ws;

    if (ws_size >= need) {
        unsigned short* embA = (unsigned short*)(ws + o_embA);
        unsigned short* embB = (unsigned short*)(ws + o_embB);
        unsigned short* xbuf = (unsigned short*)(ws + o_xbuf);
        int*   col  = (int*)(ws + o_col);
        int*   rank = (int*)(ws + o_rank);
        int*   rowp = (int*)(ws + o_row);
        int*   deg  = (int*)(ws + o_deg);
        int*   bsum = (int*)(ws + o_bsum);

        hipMemsetAsync(deg, 0, (size_t)N_NODES * 4, stream);
        hist_rank_kernel<<<FILL_BLOCKS, 256, 0, stream>>>((const int2*)edges, deg, rank);
        scan1_kernel<<<NB1, SCAN_B, 0, stream>>>(deg, rowp, bsum);
        scan23_kernel<<<NB1, SCAN_B, 0, stream>>>(rowp, bsum);
        fill_init_kernel<<<FILL_BLOCKS + INIT_BLOCKS, 256, 0, stream>>>(
            (const int2*)edges, rank, rowp, col,
            nodes, features, node_emb, feat_W, feat_b, embA);

        const int conv_grid = (N_NODES + CT - 1) / CT;   // 1563

        // iter 1: gather(bf16->bf16) + tiled conv -> embB (bf16)
        gather_x_kernel<<<N_NODES / 4, 256, 0, stream>>>(embA, rowp, col, xbuf);
        conv_tile_kernel<false><<<conv_grid, 256, 0, stream>>>(
            xbuf, conv1_W, conv1_b, pattern_emb, pattern_id, embB, nullptr);
        // iter 2: gather + tiled conv fused with cosine score -> out
        gather_x_kernel<<<N_NODES / 4, 256, 0, stream>>>(embB, rowp, col, xbuf);
        conv_tile_kernel<true><<<conv_grid, 256, 0, stream>>>(
            xbuf, conv1_W, conv1_b, pattern_emb, pattern_id, nullptr, out);
    } else {
        float* embeds = (float*)ws;
        float* agg = (float*)(ws + align256(emb_f32_bytes));
        init_embeds_kernel<<<(N_NODES * D + 255) / 256, 256, 0, stream>>>(
            nodes, features, node_emb, feat_W, feat_b, embeds);
        for (int it = 0; it < 2; ++it) {
            hipMemsetAsync(agg, 0, emb_f32_bytes, stream);
            long long total = (long long)N_EDGES * 64;
            scatter_add_kernel<<<(int)((total + 255) / 256), 256, 0, stream>>>(edges, embeds, agg);
            conv_inplace_kernel<<<2048, 256, 0, stream>>>(agg, conv1_W, conv1_b, embeds);
        }
        final_score_kernel<<<(N_NODES + 3) / 4, 256, 0, stream>>>(
            embeds, pattern_emb, pattern_id, out);
    }
}